// Round 10
// baseline (287.826 us; speedup 1.0000x reference)
//
#include <hip/hip_runtime.h>

// ---------------------------------------------------------------------------
// 3-layer GCN (DGL GraphConv, norm='both') on N=100k nodes, E=800k edges.
// Round 10:
//  - bucket records shrunk to uint2{src,eid} (8B): fill writes half the lines
//    and no longer streams w; gathers read w[wsel*E+eid] (L2/L3-hot 3.2MB).
//  - gather_L fused with gemm_{L+1}: each wave gathers its own 16 MFMA rows,
//    stages them in an XOR-swizzled LDS tile (wave-local, no barrier), then
//    MFMAs straight from LDS. Hidden-state buffer xh deleted (no HBM round
//    trip), 2 dispatches deleted.
// Per layer: y = bf16(h @ W) ; h' = relu(sum_e y[src]*w[e]*invo[src] *invi + b)
// ---------------------------------------------------------------------------

typedef short s16x8 __attribute__((ext_vector_type(8)));
typedef float f32x4 __attribute__((ext_vector_type(4)));

static constexpr int CAP = 24;   // bucket slots per node (P(deg>24)~1e-6)

__device__ __forceinline__ unsigned short f2bf(float f) {
    unsigned int u = __float_as_uint(f);
    u += 0x7FFFu + ((u >> 16) & 1u);   // round-to-nearest-even
    return (unsigned short)(u >> 16);
}
__device__ __forceinline__ float bf2f(unsigned short v) {
    return __uint_as_float((unsigned int)v << 16);
}

// ---- one kernel packs all three weight matrices into MFMA fragment order --
// Fragment mapping (same for A and B, cancels HW k-order):
//   k = kk*32 + (lane>>4)*8 + j ; col = ct*16 + (lane&15)
__global__ __launch_bounds__(256)
void pack_all(const float* __restrict__ W0, const float* __restrict__ W1,
              const float* __restrict__ W2, unsigned short* __restrict__ Wp) {
    int idx = blockIdx.x * 256 + threadIdx.x;
    if (idx < 32768) {                       // W0 / W1, PC=128, dact=128
        const float* W = (idx < 16384) ? W0 : W1;
        unsigned short* D = Wp + ((idx < 16384) ? 0 : 16384);
        int i = idx & 16383;
        int k = i >> 7, col = i & 127;
        float v = W[k * 128 + col];
        int kk = k >> 5, kr = k & 31;
        int lane = ((kr >> 3) << 4) | (col & 15);
        int ct = col >> 4, j = kr & 7;
        D[(((kk * 8) + ct) * 64 + lane) * 8 + j] = f2bf(v);
    } else if (idx < 40960) {                // W2, PC=64, dact=47
        int i = idx - 32768;
        int k = i >> 6, col = i & 63;
        float v = (col < 47) ? W2[k * 47 + col] : 0.0f;
        int kk = k >> 5, kr = k & 31;
        int lane = ((kr >> 3) << 4) | (col & 15);
        int ct = col >> 4, j = kr & 7;
        (Wp + 32768)[(((kk * 4) + ct) * 64 + lane) * 8 + j] = f2bf(v);
    }
}

// ---------------------------------------------------------------------------
// Mega-kernel: graph build (8B records) + layer-0 GEMM in one dispatch.
// ---------------------------------------------------------------------------
__global__ __launch_bounds__(256)
void mega_fill_gemm0(const int* __restrict__ src, const int* __restrict__ dst,
                     int E,
                     int* __restrict__ dego, int* __restrict__ cursor,
                     uint2* __restrict__ swe,
                     int* __restrict__ spill_cnt, int2* __restrict__ spill,
                     const float* __restrict__ x,
                     const unsigned short* __restrict__ Wp0,
                     unsigned short* __restrict__ y, int N, int gemm_blocks) {
    const int b = blockIdx.x;
    if (b % 3 == 2) {
        // ---- gemm0: y[N][128] = bf16( bf16(x) @ Wp0 ) ----
        const int gb = b / 3;
        if (gb >= gemm_blocks) return;
        const int lane = threadIdx.x & 63;
        const int wid  = threadIdx.x >> 6;
        const int row0 = gb * 64 + wid * 16;
        const int kgrp = lane >> 4;
        const int c    = lane & 15;
        int ar = row0 + c;
        if (ar > N - 1) ar = N - 1;
        const float* xrow = &x[(size_t)ar * 128];

        f32x4 acc[8];
        #pragma unroll
        for (int ct = 0; ct < 8; ++ct) acc[ct] = {0.f, 0.f, 0.f, 0.f};

        #pragma unroll
        for (int kk = 0; kk < 4; ++kk) {
            float4 u0 = *(const float4*)&xrow[kk * 32 + kgrp * 8];
            float4 u1 = *(const float4*)&xrow[kk * 32 + kgrp * 8 + 4];
            s16x8 af;
            af[0] = (short)f2bf(u0.x); af[1] = (short)f2bf(u0.y);
            af[2] = (short)f2bf(u0.z); af[3] = (short)f2bf(u0.w);
            af[4] = (short)f2bf(u1.x); af[5] = (short)f2bf(u1.y);
            af[6] = (short)f2bf(u1.z); af[7] = (short)f2bf(u1.w);
            #pragma unroll
            for (int ct = 0; ct < 8; ++ct) {
                s16x8 bf = *(const s16x8*)&Wp0[((size_t)(kk * 8 + ct) * 64 + lane) * 8];
                acc[ct] = __builtin_amdgcn_mfma_f32_16x16x32_bf16(af, bf, acc[ct], 0, 0, 0);
            }
        }
        #pragma unroll
        for (int ct = 0; ct < 8; ++ct) {
            #pragma unroll
            for (int i = 0; i < 4; ++i) {
                int row = row0 + kgrp * 4 + i;
                if (row < N) y[(size_t)row * 128 + ct * 16 + c] = f2bf(acc[ct][i]);
            }
        }
    } else {
        // ---- fill: one edge per thread, 8B record {src, eid} ----
        const int fb = b - b / 3;
        int e = fb * 256 + (int)threadIdx.x;
        if (e >= E) return;
        int s = src[e];
        int d = dst[e];
        atomicAdd(&dego[s], 1);
        int pos = atomicAdd(&cursor[d], 1);
        if (pos < CAP) {
            uint2 r; r.x = (unsigned)s; r.y = (unsigned)e;
            swe[(size_t)d * CAP + pos] = r;
        } else {
            int sp = atomicAdd(spill_cnt, 1);
            spill[sp] = make_int2(d, e);
        }
    }
}

// ---------------------------------------------------------------------------
// Fused gather + next-layer GEMM, per 64-row tile.
// Wave w gathers its own 16 MFMA rows (wave-per-node, EPG=2, shfl combine),
// finalizes (invi*acc + b, relu) to bf16 into an XOR-swizzled LDS row, then
// MFMAs its 16 rows x PCOUT straight from LDS (wave-local => no barrier).
// Gather input yin is pitch-128 bf16. Edge weight = w[eid]*rsqrt(outdeg[src]).
// ---------------------------------------------------------------------------
template<int PCOUT>
__global__ __launch_bounds__(256)
void fused_gather_gemm(const unsigned short* __restrict__ yin,
                       const uint2* __restrict__ swe,
                       const int* __restrict__ degi, const int* __restrict__ dego,
                       const int* __restrict__ spill_cnt, const int2* __restrict__ spill,
                       const int* __restrict__ srcA, const float* __restrict__ wl,
                       const float* __restrict__ bv,
                       const unsigned short* __restrict__ Wp,
                       unsigned short* __restrict__ yout, int N) {
    constexpr int CT = PCOUT / 16;
    __shared__ unsigned short hs[64 * 128];          // 16KB, XOR-swizzled rows
    const int lane = threadIdx.x & 63;
    const int wid  = threadIdx.x >> 6;
    const int row0 = blockIdx.x * 64 + wid * 16;
    if (row0 >= N) return;
    const int l = lane & 31;                         // feature lane (ushort4)
    const int g = lane >> 5;                         // edge group 0/1
    const ushort4* yv = (const ushort4*)yin;

    float4 bb = *(const float4*)&bv[l * 4];

#define EFMA(rr) do {                                                         \
        float _w = wl[(rr).y];                                                \
        int _d = dego[(rr).x]; if (_d < 1) _d = 1;                            \
        ushort4 _v = yv[(size_t)(rr).x * 32 + l];                             \
        _w *= rsqrtf((float)_d);                                              \
        a0 = fmaf(bf2f(_v.x), _w, a0);                                        \
        a1 = fmaf(bf2f(_v.y), _w, a1);                                        \
        a2 = fmaf(bf2f(_v.z), _w, a2);                                        \
        a3 = fmaf(bf2f(_v.w), _w, a3);                                        \
    } while (0)

    #pragma unroll 1
    for (int i = 0; i < 16; ++i) {
        const int n  = row0 + i;
        const int rl = wid * 16 + i;                 // LDS row
        const unsigned swz = (unsigned)((rl & 7) << 4);
        if (n < N) {
            const uint2* rec = swe + (size_t)n * CAP;
            const int dg  = degi[n];
            const int cnt = dg < CAP ? dg : CAP;
            float a0 = 0.f, a1 = 0.f, a2 = 0.f, a3 = 0.f;
            int p = g;
            for (; p + 2 < cnt; p += 4) {            // 2 edges in flight
                uint2 r0 = rec[p];
                uint2 r1 = rec[p + 2];
                EFMA(r0); EFMA(r1);
            }
            if (p < cnt) {
                uint2 r0 = rec[p];
                EFMA(r0);
            }
            if (dg > CAP && g == 0) {                // exact-overflow (empty in practice)
                int sc = *spill_cnt;
                for (int q = 0; q < sc; ++q) {
                    int2 sp = spill[q];
                    if (sp.x == n) {
                        uint2 r0; r0.x = (unsigned)srcA[sp.y]; r0.y = (unsigned)sp.y;
                        EFMA(r0);
                    }
                }
            }
            a0 += __shfl_xor(a0, 32, 64);
            a1 += __shfl_xor(a1, 32, 64);
            a2 += __shfl_xor(a2, 32, 64);
            a3 += __shfl_xor(a3, 32, 64);
            if (g == 0) {
                const float inv = rsqrtf((float)(dg < 1 ? 1 : dg));
                ushort4 o;
                o.x = f2bf(fmaxf(fmaf(a0, inv, bb.x), 0.f));
                o.y = f2bf(fmaxf(fmaf(a1, inv, bb.y), 0.f));
                o.z = f2bf(fmaxf(fmaf(a2, inv, bb.z), 0.f));
                o.w = f2bf(fmaxf(fmaf(a3, inv, bb.w), 0.f));
                *(ushort4*)((char*)hs + rl * 256 + ((unsigned)(l * 8) ^ swz)) = o;
            }
        } else if (g == 0) {
            ushort4 o; o.x = 0; o.y = 0; o.z = 0; o.w = 0;
            *(ushort4*)((char*)hs + rl * 256 + ((unsigned)(l * 8) ^ swz)) = o;
        }
    }
#undef EFMA

    // ---- MFMA from wave-local LDS rows (no barrier needed) ----
    const int kgrp = lane >> 4;
    const int c    = lane & 15;
    const int arl  = wid * 16 + c;
    const unsigned aswz = (unsigned)((arl & 7) << 4);

    f32x4 acc[CT];
    #pragma unroll
    for (int ct = 0; ct < CT; ++ct) acc[ct] = {0.f, 0.f, 0.f, 0.f};

    #pragma unroll
    for (int kk = 0; kk < 4; ++kk) {
        s16x8 af = *(const s16x8*)((const char*)hs + arl * 256 +
                                   ((unsigned)(kk * 64 + kgrp * 16) ^ aswz));
        #pragma unroll
        for (int ct = 0; ct < CT; ++ct) {
            s16x8 bf = *(const s16x8*)&Wp[((size_t)(kk * CT + ct) * 64 + lane) * 8];
            acc[ct] = __builtin_amdgcn_mfma_f32_16x16x32_bf16(af, bf, acc[ct], 0, 0, 0);
        }
    }

    #pragma unroll
    for (int ct = 0; ct < CT; ++ct) {
        #pragma unroll
        for (int i = 0; i < 4; ++i) {
            int row = row0 + kgrp * 4 + i;
            if (row < N) yout[(size_t)row * PCOUT + ct * 16 + c] = f2bf(acc[ct][i]);
        }
    }
}

// ---------------------------------------------------------------------------
// Final gather: yin pitch-64 bf16 -> d_out f32 pitch 47.
// Wave per node, TPN=16, EPG=4, shfl combine.
// ---------------------------------------------------------------------------
__global__ __launch_bounds__(256)
void gather_final(const unsigned short* __restrict__ yin,
                  const uint2* __restrict__ swe,
                  const int* __restrict__ degi, const int* __restrict__ dego,
                  const int* __restrict__ spill_cnt, const int2* __restrict__ spill,
                  const int* __restrict__ srcA, const float* __restrict__ wl,
                  const float* __restrict__ bv, float* __restrict__ out, int N) {
    const int n = blockIdx.x * 4 + (threadIdx.x >> 6);
    if (n >= N) return;
    const int t = threadIdx.x & 63;
    const int l = t & 15;
    const int g = t >> 4;                            // 0..3
    const ushort4* yv = (const ushort4*)yin;         // 16 ushort4 per row

    const uint2* rec = swe + (size_t)n * CAP;
    const int dg  = degi[n];
    const int cnt = dg < CAP ? dg : CAP;
    float a0 = 0.f, a1 = 0.f, a2 = 0.f, a3 = 0.f;

#define EFMA(rr) do {                                                         \
        float _w = wl[(rr).y];                                                \
        int _d = dego[(rr).x]; if (_d < 1) _d = 1;                            \
        ushort4 _v = yv[(size_t)(rr).x * 16 + l];                             \
        _w *= rsqrtf((float)_d);                                              \
        a0 = fmaf(bf2f(_v.x), _w, a0);                                        \
        a1 = fmaf(bf2f(_v.y), _w, a1);                                        \
        a2 = fmaf(bf2f(_v.z), _w, a2);                                        \
        a3 = fmaf(bf2f(_v.w), _w, a3);                                        \
    } while (0)

    int p = g;
    for (; p + 4 < cnt; p += 8) {
        uint2 r0 = rec[p];
        uint2 r1 = rec[p + 4];
        EFMA(r0); EFMA(r1);
    }
    if (p < cnt) {
        uint2 r0 = rec[p];
        EFMA(r0);
    }
    if (dg > CAP && g == 0) {
        int sc = *spill_cnt;
        for (int q = 0; q < sc; ++q) {
            int2 sp = spill[q];
            if (sp.x == n) {
                uint2 r0; r0.x = (unsigned)srcA[sp.y]; r0.y = (unsigned)sp.y;
                EFMA(r0);
            }
        }
    }
#undef EFMA

    a0 += __shfl_xor(a0, 16, 64);
    a1 += __shfl_xor(a1, 16, 64);
    a2 += __shfl_xor(a2, 16, 64);
    a3 += __shfl_xor(a3, 16, 64);
    a0 += __shfl_xor(a0, 32, 64);
    a1 += __shfl_xor(a1, 32, 64);
    a2 += __shfl_xor(a2, 32, 64);
    a3 += __shfl_xor(a3, 32, 64);
    if (g != 0) return;

    const float inv = rsqrtf((float)(dg < 1 ? 1 : dg));
    const int c = l * 4;
    float aa[4] = {a0, a1, a2, a3};
    #pragma unroll
    for (int j = 0; j < 4; ++j) {
        if (c + j < 47) out[(size_t)n * 47 + c + j] = fmaf(aa[j], inv, bv[c + j]);
    }
}

extern "C" void kernel_launch(void* const* d_in, const int* in_sizes, int n_in,
                              void* d_out, int out_size, void* d_ws, size_t ws_size,
                              hipStream_t stream) {
    const float* x   = (const float*)d_in[0];
    const int*   src = (const int*)d_in[1];
    const int*   dst = (const int*)d_in[2];
    const float* w   = (const float*)d_in[3];
    const float* W0  = (const float*)d_in[4];
    const float* b0  = (const float*)d_in[5];
    const float* W1  = (const float*)d_in[6];
    const float* b1  = (const float*)d_in[7];
    const float* W2  = (const float*)d_in[8];
    const float* b2  = (const float*)d_in[9];

    const int N = in_sizes[0] / 128;
    const int E = in_sizes[1];

    char* p = (char*)d_ws;
    unsigned short* yA = (unsigned short*)p; p += (size_t)N * 128 * sizeof(unsigned short);
    unsigned short* yB = (unsigned short*)p; p += (size_t)N * 128 * sizeof(unsigned short);
    unsigned short* yC = (unsigned short*)p; p += (size_t)N * 64 * sizeof(unsigned short);
    uint2* swe     = (uint2*)p;  p += (size_t)N * CAP * sizeof(uint2);
    int2*  spill   = (int2*)p;   p += (size_t)E * sizeof(int2);
    unsigned short* Wp = (unsigned short*)p; p += (size_t)(16384 * 2 + 8192) * sizeof(unsigned short);
    int*   dego    = (int*)p;    p += (size_t)N * sizeof(int);
    int*   cursor  = (int*)p;    p += (size_t)N * sizeof(int);   // becomes in-degree
    int*   spill_cnt = (int*)p;  p += 4 * sizeof(int);

    unsigned short* Wp1 = Wp + 16384;
    unsigned short* Wp2 = Wp + 32768;

    // ---- zero degree arrays + spill counter; pack all weights ----
    hipMemsetAsync(dego, 0, (2 * (size_t)N + 4) * sizeof(int), stream);
    pack_all<<<160, 256, 0, stream>>>(W0, W1, W2, Wp);

    // ---- mega: graph build + layer-0 GEMM ----
    const int gemm_blocks = (N + 63) / 64;
    const int fill_blocks = (E + 255) / 256;
    int grid = 3 * gemm_blocks;
    if (grid - grid / 3 < fill_blocks) grid = (3 * fill_blocks + 1) / 2 + 2;
    mega_fill_gemm0<<<grid, 256, 0, stream>>>(
        src, dst, E, dego, cursor, swe, spill_cnt, spill, x, Wp, yA, N, gemm_blocks);

    // ---- fused layer pipelines ----
    fused_gather_gemm<128><<<gemm_blocks, 256, 0, stream>>>(
        yA, swe, cursor, dego, spill_cnt, spill, src, w, b0, Wp1, yB, N);
    fused_gather_gemm<64><<<gemm_blocks, 256, 0, stream>>>(
        yB, swe, cursor, dego, spill_cnt, spill, src, w + E, b1, Wp2, yC, N);

    // ---- final gather -> d_out ----
    gather_final<<<(N + 3) / 4, 256, 0, stream>>>(
        yC, swe, cursor, dego, spill_cnt, spill, src, w + 2 * (size_t)E, b2,
        (float*)d_out, N);
}

// Round 11
// 261.849 us; speedup vs baseline: 1.0992x; 1.0992x over previous
//
#include <hip/hip_runtime.h>

// ---------------------------------------------------------------------------
// 3-layer GCN (DGL GraphConv, norm='both') on N=100k nodes, E=800k edges.
// Round 11 = round 9 structure (best known, 255us) + XCD-privatized out-degree
// histogram in the build (halves cross-XCD atomic line ping-pong):
//  - fill: atomicAdd(dego8[(blockIdx&7)*N + src]) -> XCD-local L2 atomics;
//    cursor atomic (placement) stays global; float4 record {src,w0,w1,w2}.
//  - reduce_dego merges the 8 copies into copy 0 (used by gathers).
//  - round-10 fusion + 8B-record reverted (both regressed: serial-chain x16
//    per wave; random w[eid] fetch +43MB).
// Per layer: y = bf16(h @ W) ; h' = bf16(relu(sum_e y[s]*w*invo[s] *invi + b))
// ---------------------------------------------------------------------------

typedef short s16x8 __attribute__((ext_vector_type(8)));
typedef float f32x4 __attribute__((ext_vector_type(4)));

static constexpr int CAP = 24;   // bucket slots per node (P(deg>24)~1e-6)

__device__ __forceinline__ unsigned short f2bf(float f) {
    unsigned int u = __float_as_uint(f);
    u += 0x7FFFu + ((u >> 16) & 1u);   // round-to-nearest-even
    return (unsigned short)(u >> 16);
}
__device__ __forceinline__ float bf2f(unsigned short v) {
    return __uint_as_float((unsigned int)v << 16);
}

// ---- one kernel packs all three weight matrices into MFMA fragment order --
// Fragment mapping (same for A and B, cancels HW k-order):
//   k = kk*32 + (lane>>4)*8 + j ; col = ct*16 + (lane&15)
__global__ __launch_bounds__(256)
void pack_all(const float* __restrict__ W0, const float* __restrict__ W1,
              const float* __restrict__ W2, unsigned short* __restrict__ Wp) {
    int idx = blockIdx.x * 256 + threadIdx.x;
    if (idx < 32768) {                       // W0 / W1, PC=128, dact=128
        const float* W = (idx < 16384) ? W0 : W1;
        unsigned short* D = Wp + ((idx < 16384) ? 0 : 16384);
        int i = idx & 16383;
        int k = i >> 7, col = i & 127;
        float v = W[k * 128 + col];
        int kk = k >> 5, kr = k & 31;
        int lane = ((kr >> 3) << 4) | (col & 15);
        int ct = col >> 4, j = kr & 7;
        D[(((kk * 8) + ct) * 64 + lane) * 8 + j] = f2bf(v);
    } else if (idx < 40960) {                // W2, PC=64, dact=47
        int i = idx - 32768;
        int k = i >> 6, col = i & 63;
        float v = (col < 47) ? W2[k * 47 + col] : 0.0f;
        int kk = k >> 5, kr = k & 31;
        int lane = ((kr >> 3) << 4) | (col & 15);
        int ct = col >> 4, j = kr & 7;
        (Wp + 32768)[(((kk * 4) + ct) * 64 + lane) * 8 + j] = f2bf(v);
    }
}

// ---------------------------------------------------------------------------
// Mega-kernel: graph build + layer-0 GEMM in one dispatch.
// blockIdx % 3 == 2 -> gemm0 block; else fill block.
// ---------------------------------------------------------------------------
__global__ __launch_bounds__(256)
void mega_fill_gemm0(const int* __restrict__ src, const int* __restrict__ dst,
                     const float* __restrict__ w, int E,
                     int* __restrict__ dego8, int* __restrict__ cursor,
                     float4* __restrict__ swb,
                     int* __restrict__ spill_cnt, int2* __restrict__ spill,
                     const float* __restrict__ x,
                     const unsigned short* __restrict__ Wp0,
                     unsigned short* __restrict__ y, int N, int gemm_blocks) {
    const int b = blockIdx.x;
    if (b % 3 == 2) {
        // ---- gemm0: y[N][128] = bf16( bf16(x) @ Wp0 ) ----
        const int gb = b / 3;
        if (gb >= gemm_blocks) return;
        const int lane = threadIdx.x & 63;
        const int wid  = threadIdx.x >> 6;
        const int row0 = gb * 64 + wid * 16;
        const int kgrp = lane >> 4;
        const int c    = lane & 15;
        int ar = row0 + c;
        if (ar > N - 1) ar = N - 1;
        const float* xrow = &x[(size_t)ar * 128];

        f32x4 acc[8];
        #pragma unroll
        for (int ct = 0; ct < 8; ++ct) acc[ct] = {0.f, 0.f, 0.f, 0.f};

        #pragma unroll
        for (int kk = 0; kk < 4; ++kk) {
            float4 u0 = *(const float4*)&xrow[kk * 32 + kgrp * 8];
            float4 u1 = *(const float4*)&xrow[kk * 32 + kgrp * 8 + 4];
            s16x8 af;
            af[0] = (short)f2bf(u0.x); af[1] = (short)f2bf(u0.y);
            af[2] = (short)f2bf(u0.z); af[3] = (short)f2bf(u0.w);
            af[4] = (short)f2bf(u1.x); af[5] = (short)f2bf(u1.y);
            af[6] = (short)f2bf(u1.z); af[7] = (short)f2bf(u1.w);
            #pragma unroll
            for (int ct = 0; ct < 8; ++ct) {
                s16x8 bf = *(const s16x8*)&Wp0[((size_t)(kk * 8 + ct) * 64 + lane) * 8];
                acc[ct] = __builtin_amdgcn_mfma_f32_16x16x32_bf16(af, bf, acc[ct], 0, 0, 0);
            }
        }
        #pragma unroll
        for (int ct = 0; ct < 8; ++ct) {
            #pragma unroll
            for (int i = 0; i < 4; ++i) {
                int row = row0 + kgrp * 4 + i;
                if (row < N) y[(size_t)row * 128 + ct * 16 + c] = f2bf(acc[ct][i]);
            }
        }
    } else {
        // ---- fill: one edge per thread; dego privatized per XCD slice ----
        const int fb = b - b / 3;
        int e = fb * 256 + (int)threadIdx.x;
        if (e >= E) return;
        int s = src[e];
        int d = dst[e];
        atomicAdd(&dego8[(size_t)(b & 7) * N + s], 1);   // XCD-local histogram
        int pos = atomicAdd(&cursor[d], 1);              // global placement
        if (pos < CAP) {
            swb[(size_t)d * CAP + pos] =
                make_float4(__int_as_float(s), w[e], w[E + e], w[2 * (size_t)E + e]);
        } else {
            int sp = atomicAdd(spill_cnt, 1);
            spill[sp] = make_int2(d, e);
        }
    }
}

// ---- merge the 8 privatized histograms into copy 0 ----
__global__ __launch_bounds__(256)
void reduce_dego(int* __restrict__ dego8, int N) {
    int i = blockIdx.x * 256 + threadIdx.x;
    if (i >= N) return;
    int s = dego8[i];
    #pragma unroll
    for (int xcd = 1; xcd < 8; ++xcd) s += dego8[(size_t)xcd * N + i];
    dego8[i] = s;
}

// ---------------------------------------------------------------------------
// LDS-free MFMA GEMM (layers 1,2): y[N][PC](bf16) = bf16( h[N][128](bf16) @ Wp )
// ---------------------------------------------------------------------------
template<int PC>
__global__ __launch_bounds__(256)
void gemm_direct(const unsigned short* __restrict__ h,
                 const unsigned short* __restrict__ Wp,
                 unsigned short* __restrict__ y, int N) {
    constexpr int CT = PC / 16;
    const int lane = threadIdx.x & 63;
    const int wid  = threadIdx.x >> 6;
    const int row0 = blockIdx.x * 64 + wid * 16;
    const int kgrp = lane >> 4;
    const int c    = lane & 15;

    int ar = row0 + c;
    if (ar > N - 1) ar = N - 1;
    const unsigned short* hrow = &h[(size_t)ar * 128 + kgrp * 8];

    f32x4 acc[CT];
    #pragma unroll
    for (int ct = 0; ct < CT; ++ct) acc[ct] = {0.f, 0.f, 0.f, 0.f};

    #pragma unroll
    for (int kk = 0; kk < 4; ++kk) {
        s16x8 af = *(const s16x8*)&hrow[kk * 32];
        #pragma unroll
        for (int ct = 0; ct < CT; ++ct) {
            s16x8 bf = *(const s16x8*)&Wp[((size_t)(kk * CT + ct) * 64 + lane) * 8];
            acc[ct] = __builtin_amdgcn_mfma_f32_16x16x32_bf16(af, bf, acc[ct], 0, 0, 0);
        }
    }

    #pragma unroll
    for (int ct = 0; ct < CT; ++ct) {
        #pragma unroll
        for (int i = 0; i < 4; ++i) {
            int row = row0 + kgrp * 4 + i;
            if (row < N) y[(size_t)row * PC + ct * 16 + c] = f2bf(acc[ct][i]);
        }
    }
}

// ---------------------------------------------------------------------------
// Wave-per-node gather + fused finalize (round-9 form).
// TPN = PC/4 lanes cover one row; EPG = 64/TPN edge groups on interleaved
// slots; 4/2/1-deep unrolled independent loads; shfl_xor combine.
// edge weight = w * rsqrt(max(outdeg[src],1)); invi = rsqrt(max(indeg,1)).
// ---------------------------------------------------------------------------
template<int PC, int WSEL, bool FINAL>
__global__ __launch_bounds__(256)
void gather_w(const unsigned short* __restrict__ yb, const float4* __restrict__ swb,
              const int* __restrict__ degi, const int* __restrict__ dego,
              const int* __restrict__ spill_cnt, const int2* __restrict__ spill,
              const int* __restrict__ src, const float* __restrict__ wl,
              const float* __restrict__ b, void* __restrict__ outp, int N) {
    constexpr int TPN = PC / 4;
    constexpr int EPG = 64 / TPN;
    const int n = blockIdx.x * 4 + (threadIdx.x >> 6);
    if (n >= N) return;
    const int t    = threadIdx.x & 63;
    const int lane = t & (TPN - 1);
    const int g    = t / TPN;

    const ushort4* yv = (const ushort4*)yb;
    const float4* rec = swb + (size_t)n * CAP;
    const int dg  = degi[n];
    const int cnt = dg < CAP ? dg : CAP;

    float a0 = 0.f, a1 = 0.f, a2 = 0.f, a3 = 0.f;
    int p = g;

#define SELW(m) ((WSEL == 0) ? (m).y : (WSEL == 1) ? (m).z : (m).w)
#define EDGE_FMA(m, v) do {                                                   \
        int _s = __float_as_int((m).x);                                       \
        int _d = dego[_s]; if (_d < 1) _d = 1;                                \
        float _w = SELW(m) * rsqrtf((float)_d);                               \
        a0 = fmaf(bf2f((v).x), _w, a0);                                       \
        a1 = fmaf(bf2f((v).y), _w, a1);                                       \
        a2 = fmaf(bf2f((v).z), _w, a2);                                       \
        a3 = fmaf(bf2f((v).w), _w, a3);                                       \
    } while (0)

    for (; p + 3 * EPG < cnt; p += 4 * EPG) {
        float4 m0 = rec[p];
        float4 m1 = rec[p + EPG];
        float4 m2 = rec[p + 2 * EPG];
        float4 m3 = rec[p + 3 * EPG];
        ushort4 v0 = yv[(size_t)__float_as_int(m0.x) * TPN + lane];
        ushort4 v1 = yv[(size_t)__float_as_int(m1.x) * TPN + lane];
        ushort4 v2 = yv[(size_t)__float_as_int(m2.x) * TPN + lane];
        ushort4 v3 = yv[(size_t)__float_as_int(m3.x) * TPN + lane];
        EDGE_FMA(m0, v0); EDGE_FMA(m1, v1); EDGE_FMA(m2, v2); EDGE_FMA(m3, v3);
    }
    for (; p + EPG < cnt; p += 2 * EPG) {
        float4 m0 = rec[p];
        float4 m1 = rec[p + EPG];
        ushort4 v0 = yv[(size_t)__float_as_int(m0.x) * TPN + lane];
        ushort4 v1 = yv[(size_t)__float_as_int(m1.x) * TPN + lane];
        EDGE_FMA(m0, v0); EDGE_FMA(m1, v1);
    }
    if (p < cnt) {
        float4 m0 = rec[p];
        ushort4 v0 = yv[(size_t)__float_as_int(m0.x) * TPN + lane];
        EDGE_FMA(m0, v0);
    }
    if (dg > CAP && g == 0) {            // exact-overflow path (empty in practice)
        int sc = *spill_cnt;
        for (int i = 0; i < sc; ++i) {
            int2 sp = spill[i];
            if (sp.x == n) {
                int e = sp.y;
                int s0 = src[e];
                int d0 = dego[s0]; if (d0 < 1) d0 = 1;
                float w0 = wl[e] * rsqrtf((float)d0);
                ushort4 v0 = yv[(size_t)s0 * TPN + lane];
                a0 = fmaf(bf2f(v0.x), w0, a0);
                a1 = fmaf(bf2f(v0.y), w0, a1);
                a2 = fmaf(bf2f(v0.z), w0, a2);
                a3 = fmaf(bf2f(v0.w), w0, a3);
            }
        }
    }
#undef EDGE_FMA
#undef SELW

    #pragma unroll
    for (int m = TPN; m < 64; m <<= 1) {
        a0 += __shfl_xor(a0, m, 64);
        a1 += __shfl_xor(a1, m, 64);
        a2 += __shfl_xor(a2, m, 64);
        a3 += __shfl_xor(a3, m, 64);
    }
    if (g != 0) return;

    const float inv = rsqrtf((float)(dg < 1 ? 1 : dg));
    if (FINAL) {
        float* out = (float*)outp;
        const int c = lane * 4;
        float aa[4] = {a0, a1, a2, a3};
        #pragma unroll
        for (int j = 0; j < 4; ++j) {
            if (c + j < 47) out[(size_t)n * 47 + c + j] = fmaf(aa[j], inv, b[c + j]);
        }
    } else {
        unsigned short* out = (unsigned short*)outp;
        float4 bb = *(const float4*)&b[lane * 4];
        float4 v;
        v.x = fmaxf(fmaf(a0, inv, bb.x), 0.f);
        v.y = fmaxf(fmaf(a1, inv, bb.y), 0.f);
        v.z = fmaxf(fmaf(a2, inv, bb.z), 0.f);
        v.w = fmaxf(fmaf(a3, inv, bb.w), 0.f);
        ushort4 o;
        o.x = f2bf(v.x); o.y = f2bf(v.y); o.z = f2bf(v.z); o.w = f2bf(v.w);
        *(ushort4*)&out[(size_t)n * PC + lane * 4] = o;
    }
}

extern "C" void kernel_launch(void* const* d_in, const int* in_sizes, int n_in,
                              void* d_out, int out_size, void* d_ws, size_t ws_size,
                              hipStream_t stream) {
    const float* x   = (const float*)d_in[0];
    const int*   src = (const int*)d_in[1];
    const int*   dst = (const int*)d_in[2];
    const float* w   = (const float*)d_in[3];
    const float* W0  = (const float*)d_in[4];
    const float* b0  = (const float*)d_in[5];
    const float* W1  = (const float*)d_in[6];
    const float* b1  = (const float*)d_in[7];
    const float* W2  = (const float*)d_in[8];
    const float* b2  = (const float*)d_in[9];

    const int N = in_sizes[0] / 128;
    const int E = in_sizes[1];

    char* p = (char*)d_ws;
    unsigned short* xh = (unsigned short*)p; p += (size_t)N * 128 * sizeof(unsigned short);
    unsigned short* y  = (unsigned short*)p; p += (size_t)N * 128 * sizeof(unsigned short);
    float4* swb    = (float4*)p; p += (size_t)N * CAP * sizeof(float4);
    int2*   spill  = (int2*)p;   p += (size_t)E * sizeof(int2);
    unsigned short* Wp = (unsigned short*)p; p += (size_t)(16384 * 2 + 8192) * sizeof(unsigned short);
    int*   dego8   = (int*)p;    p += 8 * (size_t)N * sizeof(int);   // 8 XCD copies
    int*   cursor  = (int*)p;    p += (size_t)N * sizeof(int);       // in-degree
    int*   spill_cnt = (int*)p;  p += 4 * sizeof(int);

    unsigned short* Wp1 = Wp + 16384;
    unsigned short* Wp2 = Wp + 32768;

    // ---- zero histograms (8 copies + cursor + spill_cnt); pack weights ----
    hipMemsetAsync(dego8, 0, (9 * (size_t)N + 4) * sizeof(int), stream);
    pack_all<<<160, 256, 0, stream>>>(W0, W1, W2, Wp);

    // ---- mega: graph build + layer-0 GEMM ----
    const int gemm_blocks = (N + 63) / 64;
    const int fill_blocks = (E + 255) / 256;
    int grid = 3 * gemm_blocks;
    if (grid - grid / 3 < fill_blocks) grid = (3 * fill_blocks + 1) / 2 + 2;
    mega_fill_gemm0<<<grid, 256, 0, stream>>>(
        src, dst, w, E, dego8, cursor, swb, spill_cnt, spill,
        x, Wp, y, N, gemm_blocks);

    // ---- merge privatized out-degree histograms ----
    reduce_dego<<<(N + 255) / 256, 256, 0, stream>>>(dego8, N);

    const int gather_blocks = (N + 3) / 4;

    // ---- layer 0 gather: y -> xh ----
    gather_w<128, 0, false><<<gather_blocks, 256, 0, stream>>>(
        y, swb, cursor, dego8, spill_cnt, spill, src, w, b0, xh, N);

    // ---- layer 1 ----
    gemm_direct<128><<<gemm_blocks, 256, 0, stream>>>(xh, Wp1, y, N);
    gather_w<128, 1, false><<<gather_blocks, 256, 0, stream>>>(
        y, swb, cursor, dego8, spill_cnt, spill, src, w + E, b1, xh, N);

    // ---- layer 2 ----
    gemm_direct<64><<<gemm_blocks, 256, 0, stream>>>(xh, Wp2, y, N);
    gather_w<64, 2, true><<<gather_blocks, 256, 0, stream>>>(
        y, swb, cursor, dego8, spill_cnt, spill, src, w + 2 * (size_t)E, b2,
        d_out, N);
}